// Round 14
// baseline (89.873 us; speedup 1.0000x reference)
//
#include <hip/hip_runtime.h>
#include <hip/hip_fp16.h>

#define GG 256   // NUM_GRAPHS
#define ZZDIM 32 // Z
#define KK 64    // K
#define EMBD 10  // EMB
#define SLOTS 64             // slots per 512-thr scatter block (8 lanes each)
#define MAXN 1024            // LDS node-slice capacity (sizes ~390±20; fallback kept)
#define CAP 16384            // per-graph record segment capacity (avg fill 6250, 24+ sigma)

// Record: rec[i] = (w, bits(colLocal<<17 | row)); row < 2^17 (n=100000), colLocal < 2^15.
// hs is fp16: one 64 B line per node row — each edge gather touches exactly one line.
// Round-11 lesson: NO device-scope fences (__threadfence hits all XCD L2s).
// Round-12 lesson: don't fuse per-graph kernels with n-parallel compute phases;
// BPG=1 fusion here is safe because the scatter loop is MLP-rich (gathers), not serial.

// ---------------- kernels ----------------

// node ranges per graph (binary search on sorted batch); init segment cursors
__global__ void lb_kernel(const int* __restrict__ batch, int* __restrict__ lb,
                          int* __restrict__ gcur, int n) {
    int g = threadIdx.x;  // 256 threads
    int lo = 0, hi = n;
    while (lo < hi) {
        int mid = (lo + hi) >> 1;
        if (batch[mid] < g) lo = mid + 1; else hi = mid;
    }
    lb[g] = lo;
    if (g == 0) lb[GG] = n;
    gcur[g] = g * CAP;
}

// single-pass counting-bucket: 4096 edges/block (391 blocks), g = batch[col] inline,
// block-run reservation via global cursor atomics, records into per-graph segments.
__global__ void __launch_bounds__(512) bucket_kernel(
    const int* __restrict__ row, const int* __restrict__ col, const float* __restrict__ w,
    const int* __restrict__ batch, const int* __restrict__ lb,
    int* __restrict__ gcur, float2* __restrict__ rec, int e) {
    __shared__ int lcnt[GG], lres[GG], loff[GG], lbs[GG];
    if (threadIdx.x < GG) { lcnt[threadIdx.x] = 0; loff[threadIdx.x] = 0; lbs[threadIdx.x] = lb[threadIdx.x]; }
    __syncthreads();
    const long start = (long)blockIdx.x * 4096;
    int myg[8]; unsigned myp[8];
#pragma unroll
    for (int k = 0; k < 8; ++k) {
        long i = start + k * 512 + threadIdx.x;
        int g = -1;
        if (i < e) {
            int c = col[i];
            g = batch[c];
            myp[k] = ((unsigned)(c - lbs[g]) << 17) | (unsigned)row[i];
            atomicAdd(&lcnt[g], 1);
        }
        myg[k] = g;
    }
    __syncthreads();
    if (threadIdx.x < GG && lcnt[threadIdx.x])
        lres[threadIdx.x] = atomicAdd(&gcur[threadIdx.x], lcnt[threadIdx.x]);
    __syncthreads();
#pragma unroll
    for (int k = 0; k < 8; ++k) {
        long i = start + k * 512 + threadIdx.x;
        if (i < e) {
            int g = myg[k];
            int slot = lres[g] + atomicAdd(&loff[g], 1);
            rec[slot] = make_float2(w[i], __int_as_float((int)myp[k]));
        }
    }
}

// per-graph degree via LDS accumulation over the graph's contiguous node slice;
// writes dinv = rsqrt(deg). One block per graph — NO device-scope atomics.
__global__ void degB_kernel(const float2* __restrict__ rec, const int* __restrict__ gcur,
                            const int* __restrict__ lb, float* __restrict__ dinv) {
    __shared__ float dl[MAXN];
    const int g = blockIdx.x;
    const int ns = lb[g], ne = lb[g + 1], sz = ne - ns;
    const long lo = (long)g * CAP;
    const long hi = gcur[g];
    if (sz <= MAXN) {
        for (int t = threadIdx.x; t < sz; t += 256) dl[t] = 2.0f;  // improved self-loop fill
        __syncthreads();
        for (long it = lo + threadIdx.x; it < hi; it += 256) {
            float2 r = rec[it];
            atomicAdd(&dl[(unsigned)__float_as_int(r.y) >> 17], r.x);
        }
        __syncthreads();
        for (int t = threadIdx.x; t < sz; t += 256) dinv[ns + t] = rsqrtf(dl[t]);
    } else {  // fallback (never expected at n/GG ~ 390)
        for (int t = threadIdx.x; t < sz; t += 256) dinv[ns + t] = 2.0f;
        __syncthreads();
        for (long it = lo + threadIdx.x; it < hi; it += 256) {
            float2 r = rec[it];
            atomicAdd(&dinv[ns + ((unsigned)__float_as_int(r.y) >> 17)], r.x);
        }
        __syncthreads();
        for (int t = threadIdx.x; t < sz; t += 256) dinv[ns + t] = rsqrtf(dinv[ns + t]);
    }
}

// hs16[i, 2zp..2zp+1] = half2( dinv[i] * sum_j embed[x[i],j] * Wc[j, 2zp..2zp+1] )
__global__ void hs_kernel(const int* __restrict__ x, const float* __restrict__ emb,
                          const float* __restrict__ Wc, const float* __restrict__ dinv,
                          __half2* __restrict__ hs16, int n) {
    int tid = blockIdx.x * blockDim.x + threadIdx.x;
    int i = tid >> 4, zp = tid & 15;     // 16 half2 per node row
    if (i >= n) return;
    float d = dinv[i];
    int xi = x[i];
    const float* er = emb + (long)xi * EMBD;
    float a0 = 0.f, a1 = 0.f;
#pragma unroll
    for (int j = 0; j < EMBD; ++j) {
        float ej = er[j];
        a0 += ej * Wc[j * ZZDIM + 2 * zp];
        a1 += ej * Wc[j * ZZDIM + 2 * zp + 1];
    }
    hs16[(long)i * 16 + zp] = __floats2half2_rn(d * a0, d * a1);
}

// One block per graph: register-accumulation scatter over fp16 hs rows, in-block
// reduce, then pooled+logits written directly (all block-local — no fences).
__global__ void __launch_bounds__(512) scatter_kernel(
    const float2* __restrict__ rec, const int* __restrict__ gcur,
    const int* __restrict__ lb, const float* __restrict__ dinv,
    const uint2* __restrict__ hsq, const float* __restrict__ bc,
    const float* __restrict__ Wr, float* __restrict__ out) {
    __shared__ float dl[MAXN];
    const int z4   = threadIdx.x & 7;        // channel quad 0..7
    const int slot = threadIdx.x >> 3;       // 0..63
    const int g = blockIdx.x;
    const int ns = lb[g], ne = lb[g + 1], sz = ne - ns;
    const bool inl = (sz <= MAXN);
    if (inl) for (int t = threadIdx.x; t < sz; t += 512) dl[t] = dinv[ns + t];
    __syncthreads();

    float4 acc = make_float4(0.f, 0.f, 0.f, 0.f);

#define GATHER4(pp) hsq[(long)((pp) & 0x1FFFFu) * 8 + z4]
#define ACCUM(c, v) do {                                              \
        float2 f0 = __half22float2(*(const __half2*)&(v).x);          \
        float2 f1 = __half22float2(*(const __half2*)&(v).y);          \
        acc.x = fmaf((c), f0.x, acc.x); acc.y = fmaf((c), f0.y, acc.y);\
        acc.z = fmaf((c), f1.x, acc.z); acc.w = fmaf((c), f1.y, acc.w);\
    } while (0)

    // edges of graph g (bucketed segment [g*CAP, gcur[g]))
    const long lo = (long)g * CAP;
    const long hi = gcur[g];
    long it = lo + slot;
    for (; it + 3L * SLOTS < hi; it += 4L * SLOTS) {
        float2 r0 = rec[it];
        float2 r1 = rec[it + SLOTS];
        float2 r2 = rec[it + 2L * SLOTS];
        float2 r3 = rec[it + 3L * SLOTS];
        unsigned p0 = (unsigned)__float_as_int(r0.y), p1 = (unsigned)__float_as_int(r1.y);
        unsigned p2 = (unsigned)__float_as_int(r2.y), p3 = (unsigned)__float_as_int(r3.y);
        uint2 v0 = GATHER4(p0);
        uint2 v1 = GATHER4(p1);
        uint2 v2 = GATHER4(p2);
        uint2 v3 = GATHER4(p3);
        float c0 = r0.x * (inl ? dl[p0 >> 17] : dinv[ns + (p0 >> 17)]);
        float c1 = r1.x * (inl ? dl[p1 >> 17] : dinv[ns + (p1 >> 17)]);
        float c2 = r2.x * (inl ? dl[p2 >> 17] : dinv[ns + (p2 >> 17)]);
        float c3 = r3.x * (inl ? dl[p3 >> 17] : dinv[ns + (p3 >> 17)]);
        ACCUM(c0, v0); ACCUM(c1, v1); ACCUM(c2, v2); ACCUM(c3, v3);
    }
    for (; it < hi; it += SLOTS) {
        float2 r = rec[it];
        unsigned p = (unsigned)__float_as_int(r.y);
        uint2 v = GATHER4(p);
        float c = r.x * (inl ? dl[p >> 17] : dinv[ns + (p >> 17)]);
        ACCUM(c, v);
    }

    // self-loops: nodes of graph g are contiguous [ns, ne)
    for (long i = ns + slot; i < ne; i += SLOTS) {
        float c2v = 2.0f * (inl ? dl[i - ns] : dinv[i]);
        uint2 v = hsq[i * 8 + z4];
        ACCUM(c2v, v);
    }
#undef GATHER4
#undef ACCUM

    // reduce 64 slots -> 32 channels
    __shared__ float4 s[SLOTS][8];
    __shared__ float4 s2[8][8];
    __shared__ float p[ZZDIM];
    s[slot][z4] = acc;
    __syncthreads();
    if (threadIdx.x < 64) {
        int j = threadIdx.x & 7, part = threadIdx.x >> 3;
        float4 a = make_float4(0.f, 0.f, 0.f, 0.f);
#pragma unroll
        for (int k = 0; k < 8; ++k) {
            float4 b = s[part * 8 + k][j];
            a.x += b.x; a.y += b.y; a.z += b.z; a.w += b.w;
        }
        s2[part][j] = a;
    }
    __syncthreads();
    // pooled: thread t < 32 sums its channel across the 8 parts, writes out + LDS
    if (threadIdx.x < ZZDIM) {
        int t = threadIdx.x;
        int j = t >> 2, comp = t & 3;
        float a = 0.f;
#pragma unroll
        for (int k = 0; k < 8; ++k) {
            const float4 b = s2[k][j];
            a += (comp == 0) ? b.x : (comp == 1) ? b.y : (comp == 2) ? b.z : b.w;
        }
        float v = (sz > 0) ? (bc[t] + a / (float)sz) : 0.f;
        out[g * ZZDIM + t] = v;
        p[t] = v;
    }
    __syncthreads();
    // logits: thread t < 64
    if (threadIdx.x < KK) {
        int t = threadIdx.x;
        float a = 0.f;
#pragma unroll
        for (int zz = 0; zz < ZZDIM; ++zz) a += p[zz] * Wr[zz * KK + t];
        out[GG * ZZDIM + g * KK + t] = a;
    }
}

// ---------------- launch ----------------

extern "C" void kernel_launch(void* const* d_in, const int* in_sizes, int n_in,
                              void* d_out, int out_size, void* d_ws, size_t ws_size,
                              hipStream_t stream) {
    const int*   x     = (const int*)d_in[0];
    const int*   ei    = (const int*)d_in[1];   // [2,E]: rows then cols
    const float* ew    = (const float*)d_in[2];
    const int*   batch = (const int*)d_in[3];
    const float* emb   = (const float*)d_in[4];
    const float* Wc    = (const float*)d_in[5];
    const float* bc    = (const float*)d_in[6];
    const float* Wr    = (const float*)d_in[7];
    float* out = (float*)d_out;

    const int n = in_sizes[0];
    const int e = in_sizes[2];

    float* ws   = (float*)d_ws;
    __half2* hs16 = (__half2*)ws;            // n*16 half2 = 16n words (16 B aligned)
    float* dinv = ws + 16L * n;              // n
    int*  lb    = (int*)(ws + 17L * n);      // GG+1
    int*  gcur  = lb + GG + 1;               // GG
    long rbase = 17L * n + (2 * GG + 1);
    rbase = (rbase + 63) & ~63L;
    float2* rec = (float2*)(ws + rbase);     // GG*CAP records (8 B each)

    lb_kernel<<<1, 256, 0, stream>>>(batch, lb, gcur, n);
    bucket_kernel<<<(e + 4095) / 4096, 512, 0, stream>>>(ei, ei + e, ew, batch, lb, gcur, rec, e);
    degB_kernel<<<GG, 256, 0, stream>>>(rec, gcur, lb, dinv);
    hs_kernel<<<(n * 16 + 255) / 256, 256, 0, stream>>>(x, emb, Wc, dinv, hs16, n);
    scatter_kernel<<<GG, 512, 0, stream>>>(rec, gcur, lb, dinv, (const uint2*)hs16, bc, Wr, out);
}

// Round 16
// 85.787 us; speedup vs baseline: 1.0476x; 1.0476x over previous
//
#include <hip/hip_runtime.h>
#include <hip/hip_fp16.h>

#define GG 256   // NUM_GRAPHS
#define ZZDIM 32 // Z
#define KK 64    // K
#define EMBD 10  // EMB
#define BPG 4                // scatter blocks per graph
#define SGRID (GG * BPG)     // 1024 scatter blocks
#define SLOTS 64             // slots per 512-thr scatter block (8 lanes each)
#define SPG (BPG * SLOTS)    // 256 slots per graph
#define MAXN 1024            // LDS node-slice capacity (sizes ~390±20; fallback kept)
#define CAP 16384            // per-graph record segment capacity (avg fill 6250, 24+ sigma)

// Record: rec[i] = (w, bits(colLocal<<17 | row)); row < 2^17 (n=100000), colLocal < 2^15.
// hs is fp16: one 64 B line per node row — each edge gather touches exactly one line.
// R11 lesson: NO device-scope fences (__threadfence = L2 writeback storm across XCDs).
// R12 lesson: don't fuse per-graph kernels with n-parallel compute (occupancy collapse).
// R14 lesson: scatter needs BPG=4 (32 waves/CU); BPG=1 costs ~6 us.
// R15 lesson: hipLaunchCooperativeKernel silently no-ops under this harness's graph
// capture — launch gaps are irreducible; keep the 6-launch structure.

// ---------------- kernels ----------------

// node ranges per graph (binary search on sorted batch); init segment cursors
__global__ void lb_kernel(const int* __restrict__ batch, int* __restrict__ lb,
                          int* __restrict__ gcur, int n) {
    int g = threadIdx.x;  // 256 threads
    int lo = 0, hi = n;
    while (lo < hi) {
        int mid = (lo + hi) >> 1;
        if (batch[mid] < g) lo = mid + 1; else hi = mid;
    }
    lb[g] = lo;
    if (g == 0) lb[GG] = n;
    gcur[g] = g * CAP;
}

// single-pass counting-bucket: 4096 edges/block (391 blocks), g = batch[col] inline,
// block-run reservation via global cursor atomics, records into per-graph segments.
__global__ void __launch_bounds__(512) bucket_kernel(
    const int* __restrict__ row, const int* __restrict__ col, const float* __restrict__ w,
    const int* __restrict__ batch, const int* __restrict__ lb,
    int* __restrict__ gcur, float2* __restrict__ rec, int e) {
    __shared__ int lcnt[GG], lres[GG], loff[GG], lbs[GG];
    if (threadIdx.x < GG) { lcnt[threadIdx.x] = 0; loff[threadIdx.x] = 0; lbs[threadIdx.x] = lb[threadIdx.x]; }
    __syncthreads();
    const long start = (long)blockIdx.x * 4096;
    int myg[8]; unsigned myp[8];
#pragma unroll
    for (int k = 0; k < 8; ++k) {
        long i = start + k * 512 + threadIdx.x;
        int g = -1;
        if (i < e) {
            int c = col[i];
            g = batch[c];
            myp[k] = ((unsigned)(c - lbs[g]) << 17) | (unsigned)row[i];
            atomicAdd(&lcnt[g], 1);
        }
        myg[k] = g;
    }
    __syncthreads();
    if (threadIdx.x < GG && lcnt[threadIdx.x])
        lres[threadIdx.x] = atomicAdd(&gcur[threadIdx.x], lcnt[threadIdx.x]);
    __syncthreads();
#pragma unroll
    for (int k = 0; k < 8; ++k) {
        long i = start + k * 512 + threadIdx.x;
        if (i < e) {
            int g = myg[k];
            int slot = lres[g] + atomicAdd(&loff[g], 1);
            rec[slot] = make_float2(w[i], __int_as_float((int)myp[k]));
        }
    }
}

// per-graph degree via LDS accumulation over the graph's contiguous node slice;
// writes dinv = rsqrt(deg). One block per graph — NO device-scope atomics.
__global__ void degB_kernel(const float2* __restrict__ rec, const int* __restrict__ gcur,
                            const int* __restrict__ lb, float* __restrict__ dinv) {
    __shared__ float dl[MAXN];
    const int g = blockIdx.x;
    const int ns = lb[g], ne = lb[g + 1], sz = ne - ns;
    const long lo = (long)g * CAP;
    const long hi = gcur[g];
    if (sz <= MAXN) {
        for (int t = threadIdx.x; t < sz; t += 256) dl[t] = 2.0f;  // improved self-loop fill
        __syncthreads();
        for (long it = lo + threadIdx.x; it < hi; it += 256) {
            float2 r = rec[it];
            atomicAdd(&dl[(unsigned)__float_as_int(r.y) >> 17], r.x);
        }
        __syncthreads();
        for (int t = threadIdx.x; t < sz; t += 256) dinv[ns + t] = rsqrtf(dl[t]);
    } else {  // fallback (never expected at n/GG ~ 390)
        for (int t = threadIdx.x; t < sz; t += 256) dinv[ns + t] = 2.0f;
        __syncthreads();
        for (long it = lo + threadIdx.x; it < hi; it += 256) {
            float2 r = rec[it];
            atomicAdd(&dinv[ns + ((unsigned)__float_as_int(r.y) >> 17)], r.x);
        }
        __syncthreads();
        for (int t = threadIdx.x; t < sz; t += 256) dinv[ns + t] = rsqrtf(dinv[ns + t]);
    }
}

// hs16[i, 2zp..2zp+1] = half2( dinv[i] * sum_j embed[x[i],j] * Wc[j, 2zp..2zp+1] )
__global__ void hs_kernel(const int* __restrict__ x, const float* __restrict__ emb,
                          const float* __restrict__ Wc, const float* __restrict__ dinv,
                          __half2* __restrict__ hs16, int n) {
    int tid = blockIdx.x * blockDim.x + threadIdx.x;
    int i = tid >> 4, zp = tid & 15;     // 16 half2 per node row
    if (i >= n) return;
    float d = dinv[i];
    int xi = x[i];
    const float* er = emb + (long)xi * EMBD;
    float a0 = 0.f, a1 = 0.f;
#pragma unroll
    for (int j = 0; j < EMBD; ++j) {
        float ej = er[j];
        a0 += ej * Wc[j * ZZDIM + 2 * zp];
        a1 += ej * Wc[j * ZZDIM + 2 * zp + 1];
    }
    hs16[(long)i * 16 + zp] = __floats2half2_rn(d * a0, d * a1);
}

// Register-accumulation scatter over fp16 hs rows (64 B): 8 lanes x uint2 per edge.
__global__ void __launch_bounds__(512) scatter_kernel(
    const float2* __restrict__ rec, const int* __restrict__ gcur,
    const int* __restrict__ lb, const float* __restrict__ dinv,
    const uint2* __restrict__ hsq, float* __restrict__ partial) {
    __shared__ float dl[MAXN];
    const int z4   = threadIdx.x & 7;        // channel quad 0..7
    const int slot = threadIdx.x >> 3;       // 0..63
    const int g = blockIdx.x >> 2;
    const int q = blockIdx.x & 3;
    const int sg = q * SLOTS + slot;         // slot-in-graph 0..255
    const int ns = lb[g], ne = lb[g + 1], sz = ne - ns;
    const bool inl = (sz <= MAXN);
    if (inl) for (int t = threadIdx.x; t < sz; t += 512) dl[t] = dinv[ns + t];
    __syncthreads();

    float4 acc = make_float4(0.f, 0.f, 0.f, 0.f);

#define GATHER4(pp) hsq[(long)((pp) & 0x1FFFFu) * 8 + z4]
#define ACCUM(c, v) do {                                              \
        float2 f0 = __half22float2(*(const __half2*)&(v).x);          \
        float2 f1 = __half22float2(*(const __half2*)&(v).y);          \
        acc.x = fmaf((c), f0.x, acc.x); acc.y = fmaf((c), f0.y, acc.y);\
        acc.z = fmaf((c), f1.x, acc.z); acc.w = fmaf((c), f1.y, acc.w);\
    } while (0)

    // edges of graph g (bucketed segment [g*CAP, gcur[g]))
    const long lo = (long)g * CAP;
    const long hi = gcur[g];
    long it = lo + sg;
    for (; it + 3L * SPG < hi; it += 4L * SPG) {
        float2 r0 = rec[it];
        float2 r1 = rec[it + SPG];
        float2 r2 = rec[it + 2L * SPG];
        float2 r3 = rec[it + 3L * SPG];
        unsigned p0 = (unsigned)__float_as_int(r0.y), p1 = (unsigned)__float_as_int(r1.y);
        unsigned p2 = (unsigned)__float_as_int(r2.y), p3 = (unsigned)__float_as_int(r3.y);
        uint2 v0 = GATHER4(p0);
        uint2 v1 = GATHER4(p1);
        uint2 v2 = GATHER4(p2);
        uint2 v3 = GATHER4(p3);
        float c0 = r0.x * (inl ? dl[p0 >> 17] : dinv[ns + (p0 >> 17)]);
        float c1 = r1.x * (inl ? dl[p1 >> 17] : dinv[ns + (p1 >> 17)]);
        float c2 = r2.x * (inl ? dl[p2 >> 17] : dinv[ns + (p2 >> 17)]);
        float c3 = r3.x * (inl ? dl[p3 >> 17] : dinv[ns + (p3 >> 17)]);
        ACCUM(c0, v0); ACCUM(c1, v1); ACCUM(c2, v2); ACCUM(c3, v3);
    }
    for (; it < hi; it += SPG) {
        float2 r = rec[it];
        unsigned p = (unsigned)__float_as_int(r.y);
        uint2 v = GATHER4(p);
        float c = r.x * (inl ? dl[p >> 17] : dinv[ns + (p >> 17)]);
        ACCUM(c, v);
    }

    // self-loops: nodes of graph g are contiguous [ns, ne)
    for (long i = ns + sg; i < ne; i += SPG) {
        float c2v = 2.0f * (inl ? dl[i - ns] : dinv[i]);
        uint2 v = hsq[i * 8 + z4];
        ACCUM(c2v, v);
    }
#undef GATHER4
#undef ACCUM

    // reduce 64 slots -> 32 channels
    __shared__ float4 s[SLOTS][8];
    __shared__ float4 s2[8][8];
    s[slot][z4] = acc;
    __syncthreads();
    if (threadIdx.x < 64) {
        int j = threadIdx.x & 7, part = threadIdx.x >> 3;
        float4 a = make_float4(0.f, 0.f, 0.f, 0.f);
#pragma unroll
        for (int k = 0; k < 8; ++k) {
            float4 b = s[part * 8 + k][j];
            a.x += b.x; a.y += b.y; a.z += b.z; a.w += b.w;
        }
        s2[part][j] = a;
    }
    __syncthreads();
    if (threadIdx.x < 8) {
        int j = threadIdx.x;
        float4 a = make_float4(0.f, 0.f, 0.f, 0.f);
#pragma unroll
        for (int k = 0; k < 8; ++k) {
            float4 b = s2[k][j];
            a.x += b.x; a.y += b.y; a.z += b.z; a.w += b.w;
        }
        *(float4*)&partial[(long)blockIdx.x * ZZDIM + j * 4] = a;
    }
}

// sum BPG partials per graph -> pooled -> logits
__global__ void finalize_kernel(const float* __restrict__ partial, const int* __restrict__ lb,
                                const float* __restrict__ bc, const float* __restrict__ Wr,
                                float* __restrict__ out) {
    int g = blockIdx.x;
    int t = threadIdx.x;  // 64 threads
    __shared__ float p[ZZDIM];
    if (t < ZZDIM) {
        float a = 0.f;
#pragma unroll
        for (int q = 0; q < BPG; ++q) a += partial[(long)(g * BPG + q) * ZZDIM + t];
        float c = (float)(lb[g + 1] - lb[g]);
        float v = (c > 0.f) ? (bc[t] + a / c) : 0.f;
        out[g * ZZDIM + t] = v;
        p[t] = v;
    }
    __syncthreads();
    float a = 0.f;
#pragma unroll
    for (int zz = 0; zz < ZZDIM; ++zz) a += p[zz] * Wr[zz * KK + t];
    out[GG * ZZDIM + g * KK + t] = a;
}

// ---------------- launch ----------------

extern "C" void kernel_launch(void* const* d_in, const int* in_sizes, int n_in,
                              void* d_out, int out_size, void* d_ws, size_t ws_size,
                              hipStream_t stream) {
    const int*   x     = (const int*)d_in[0];
    const int*   ei    = (const int*)d_in[1];   // [2,E]: rows then cols
    const float* ew    = (const float*)d_in[2];
    const int*   batch = (const int*)d_in[3];
    const float* emb   = (const float*)d_in[4];
    const float* Wc    = (const float*)d_in[5];
    const float* bc    = (const float*)d_in[6];
    const float* Wr    = (const float*)d_in[7];
    float* out = (float*)d_out;

    const int n = in_sizes[0];
    const int e = in_sizes[2];

    float* ws   = (float*)d_ws;
    __half2* hs16 = (__half2*)ws;            // n*16 half2 = 16n words (16 B aligned)
    float* dinv = ws + 16L * n;              // n
    int*  lb    = (int*)(ws + 17L * n);      // GG+1
    int*  gcur  = lb + GG + 1;               // GG
    long rbase = 17L * n + (2 * GG + 1);
    rbase = (rbase + 63) & ~63L;
    float2* rec = (float2*)(ws + rbase);     // GG*CAP records (8 B each)
    long pbase = rbase + 2L * GG * CAP;
    pbase = (pbase + 63) & ~63L;
    float* partial = ws + pbase;             // SGRID*32 floats

    lb_kernel<<<1, 256, 0, stream>>>(batch, lb, gcur, n);
    bucket_kernel<<<(e + 4095) / 4096, 512, 0, stream>>>(ei, ei + e, ew, batch, lb, gcur, rec, e);
    degB_kernel<<<GG, 256, 0, stream>>>(rec, gcur, lb, dinv);
    hs_kernel<<<(n * 16 + 255) / 256, 256, 0, stream>>>(x, emb, Wc, dinv, hs16, n);
    scatter_kernel<<<SGRID, 512, 0, stream>>>(rec, gcur, lb, dinv, (const uint2*)hs16, partial);
    finalize_kernel<<<GG, KK, 0, stream>>>(partial, lb, bc, Wr, out);
}

// Round 17
// 84.383 us; speedup vs baseline: 1.0651x; 1.0166x over previous
//
#include <hip/hip_runtime.h>
#include <hip/hip_fp16.h>

#define GG 256   // NUM_GRAPHS
#define ZZDIM 32 // Z
#define KK 64    // K
#define EMBD 10  // EMB
#define BPG 4                // scatter blocks per graph
#define SGRID (GG * BPG)     // 1024 scatter blocks
#define SLOTS 64             // slots per 512-thr scatter block (8 lanes each)
#define SPG (BPG * SLOTS)    // 256 slots per graph
#define MAXN 1024            // LDS node-slice capacity (sizes ~390±20; fallback kept)
#define CAP 16384            // per-graph record segment capacity (avg fill 6250, 24+ sigma)

// Record: rec[i] = (w, bits(colLocal<<17 | row)); row < 2^17 (n=100000), colLocal < 2^15.
// hs is fp16: one 64 B line per node row — each edge gather touches exactly one line.
// R11 lesson: NO device-scope fences (__threadfence = L2 writeback storm across XCDs).
// R12 lesson: don't fuse per-graph kernels with n-parallel compute (occupancy collapse).
// R14 lesson: scatter needs BPG=4 (32 waves/CU); BPG=1 costs ~6 us.
// R15 lesson: hipLaunchCooperativeKernel silently no-ops under this harness's graph
// capture — launch gaps are irreducible; keep the 6-launch structure.
// R16 lesson: bucket 8192 edges/block beats 4096 (fewer LDS-counter passes).

// ---------------- kernels ----------------

// node ranges per graph (binary search on sorted batch); init segment cursors
__global__ void lb_kernel(const int* __restrict__ batch, int* __restrict__ lb,
                          int* __restrict__ gcur, int n) {
    int g = threadIdx.x;  // 256 threads
    int lo = 0, hi = n;
    while (lo < hi) {
        int mid = (lo + hi) >> 1;
        if (batch[mid] < g) lo = mid + 1; else hi = mid;
    }
    lb[g] = lo;
    if (g == 0) lb[GG] = n;
    gcur[g] = g * CAP;
}

// single-pass counting-bucket: g = batch[col] inline (L2-hit), block-run reservation
// via 256 global cursor atomics, records into fixed-capacity per-graph segments.
__global__ void __launch_bounds__(512) bucket_kernel(
    const int* __restrict__ row, const int* __restrict__ col, const float* __restrict__ w,
    const int* __restrict__ batch, const int* __restrict__ lb,
    int* __restrict__ gcur, float2* __restrict__ rec, int e) {
    __shared__ int lcnt[GG], lres[GG], loff[GG], lbs[GG];
    for (int t = threadIdx.x; t < GG; t += 512) { lcnt[t] = 0; loff[t] = 0; lbs[t] = lb[t]; }
    __syncthreads();
    const long start = (long)blockIdx.x * 8192;
    int myg[16]; unsigned myp[16];
#pragma unroll
    for (int k = 0; k < 16; ++k) {
        long i = start + k * 512 + threadIdx.x;
        int g = -1;
        if (i < e) {
            int c = col[i];
            g = batch[c];
            myp[k] = ((unsigned)(c - lbs[g]) << 17) | (unsigned)row[i];
            atomicAdd(&lcnt[g], 1);
        }
        myg[k] = g;
    }
    __syncthreads();
    for (int t = threadIdx.x; t < GG; t += 512)
        if (lcnt[t]) lres[t] = atomicAdd(&gcur[t], lcnt[t]);
    __syncthreads();
#pragma unroll
    for (int k = 0; k < 16; ++k) {
        long i = start + k * 512 + threadIdx.x;
        if (i < e) {
            int g = myg[k];
            int slot = lres[g] + atomicAdd(&loff[g], 1);
            rec[slot] = make_float2(w[i], __int_as_float((int)myp[k]));
        }
    }
}

// per-graph degree via LDS accumulation over the graph's contiguous node slice;
// writes dinv = rsqrt(deg). One block per graph — NO device-scope atomics.
__global__ void degB_kernel(const float2* __restrict__ rec, const int* __restrict__ gcur,
                            const int* __restrict__ lb, float* __restrict__ dinv) {
    __shared__ float dl[MAXN];
    const int g = blockIdx.x;
    const int ns = lb[g], ne = lb[g + 1], sz = ne - ns;
    const long lo = (long)g * CAP;
    const long hi = gcur[g];
    if (sz <= MAXN) {
        for (int t = threadIdx.x; t < sz; t += 256) dl[t] = 2.0f;  // improved self-loop fill
        __syncthreads();
        for (long it = lo + threadIdx.x; it < hi; it += 256) {
            float2 r = rec[it];
            atomicAdd(&dl[(unsigned)__float_as_int(r.y) >> 17], r.x);
        }
        __syncthreads();
        for (int t = threadIdx.x; t < sz; t += 256) dinv[ns + t] = rsqrtf(dl[t]);
    } else {  // fallback (never expected at n/GG ~ 390)
        for (int t = threadIdx.x; t < sz; t += 256) dinv[ns + t] = 2.0f;
        __syncthreads();
        for (long it = lo + threadIdx.x; it < hi; it += 256) {
            float2 r = rec[it];
            atomicAdd(&dinv[ns + ((unsigned)__float_as_int(r.y) >> 17)], r.x);
        }
        __syncthreads();
        for (int t = threadIdx.x; t < sz; t += 256) dinv[ns + t] = rsqrtf(dinv[ns + t]);
    }
}

// hs16[i, 2zp..2zp+1] = half2( dinv[i] * sum_j embed[x[i],j] * Wc[j, 2zp..2zp+1] )
__global__ void hs_kernel(const int* __restrict__ x, const float* __restrict__ emb,
                          const float* __restrict__ Wc, const float* __restrict__ dinv,
                          __half2* __restrict__ hs16, int n) {
    int tid = blockIdx.x * blockDim.x + threadIdx.x;
    int i = tid >> 4, zp = tid & 15;     // 16 half2 per node row
    if (i >= n) return;
    float d = dinv[i];
    int xi = x[i];
    const float* er = emb + (long)xi * EMBD;
    float a0 = 0.f, a1 = 0.f;
#pragma unroll
    for (int j = 0; j < EMBD; ++j) {
        float ej = er[j];
        a0 += ej * Wc[j * ZZDIM + 2 * zp];
        a1 += ej * Wc[j * ZZDIM + 2 * zp + 1];
    }
    hs16[(long)i * 16 + zp] = __floats2half2_rn(d * a0, d * a1);
}

// Register-accumulation scatter over fp16 hs rows (64 B): 8 lanes x uint2 per edge.
__global__ void __launch_bounds__(512) scatter_kernel(
    const float2* __restrict__ rec, const int* __restrict__ gcur,
    const int* __restrict__ lb, const float* __restrict__ dinv,
    const uint2* __restrict__ hsq, float* __restrict__ partial) {
    __shared__ float dl[MAXN];
    const int z4   = threadIdx.x & 7;        // channel quad 0..7
    const int slot = threadIdx.x >> 3;       // 0..63
    const int g = blockIdx.x >> 2;
    const int q = blockIdx.x & 3;
    const int sg = q * SLOTS + slot;         // slot-in-graph 0..255
    const int ns = lb[g], ne = lb[g + 1], sz = ne - ns;
    const bool inl = (sz <= MAXN);
    if (inl) for (int t = threadIdx.x; t < sz; t += 512) dl[t] = dinv[ns + t];
    __syncthreads();

    float4 acc = make_float4(0.f, 0.f, 0.f, 0.f);

#define GATHER4(pp) hsq[(long)((pp) & 0x1FFFFu) * 8 + z4]
#define ACCUM(c, v) do {                                              \
        float2 f0 = __half22float2(*(const __half2*)&(v).x);          \
        float2 f1 = __half22float2(*(const __half2*)&(v).y);          \
        acc.x = fmaf((c), f0.x, acc.x); acc.y = fmaf((c), f0.y, acc.y);\
        acc.z = fmaf((c), f1.x, acc.z); acc.w = fmaf((c), f1.y, acc.w);\
    } while (0)

    // edges of graph g (bucketed segment [g*CAP, gcur[g]))
    const long lo = (long)g * CAP;
    const long hi = gcur[g];
    long it = lo + sg;
    for (; it + 3L * SPG < hi; it += 4L * SPG) {
        float2 r0 = rec[it];
        float2 r1 = rec[it + SPG];
        float2 r2 = rec[it + 2L * SPG];
        float2 r3 = rec[it + 3L * SPG];
        unsigned p0 = (unsigned)__float_as_int(r0.y), p1 = (unsigned)__float_as_int(r1.y);
        unsigned p2 = (unsigned)__float_as_int(r2.y), p3 = (unsigned)__float_as_int(r3.y);
        uint2 v0 = GATHER4(p0);
        uint2 v1 = GATHER4(p1);
        uint2 v2 = GATHER4(p2);
        uint2 v3 = GATHER4(p3);
        float c0 = r0.x * (inl ? dl[p0 >> 17] : dinv[ns + (p0 >> 17)]);
        float c1 = r1.x * (inl ? dl[p1 >> 17] : dinv[ns + (p1 >> 17)]);
        float c2 = r2.x * (inl ? dl[p2 >> 17] : dinv[ns + (p2 >> 17)]);
        float c3 = r3.x * (inl ? dl[p3 >> 17] : dinv[ns + (p3 >> 17)]);
        ACCUM(c0, v0); ACCUM(c1, v1); ACCUM(c2, v2); ACCUM(c3, v3);
    }
    for (; it < hi; it += SPG) {
        float2 r = rec[it];
        unsigned p = (unsigned)__float_as_int(r.y);
        uint2 v = GATHER4(p);
        float c = r.x * (inl ? dl[p >> 17] : dinv[ns + (p >> 17)]);
        ACCUM(c, v);
    }

    // self-loops: nodes of graph g are contiguous [ns, ne)
    for (long i = ns + sg; i < ne; i += SPG) {
        float c2v = 2.0f * (inl ? dl[i - ns] : dinv[i]);
        uint2 v = hsq[i * 8 + z4];
        ACCUM(c2v, v);
    }
#undef GATHER4
#undef ACCUM

    // reduce 64 slots -> 32 channels
    __shared__ float4 s[SLOTS][8];
    __shared__ float4 s2[8][8];
    s[slot][z4] = acc;
    __syncthreads();
    if (threadIdx.x < 64) {
        int j = threadIdx.x & 7, part = threadIdx.x >> 3;
        float4 a = make_float4(0.f, 0.f, 0.f, 0.f);
#pragma unroll
        for (int k = 0; k < 8; ++k) {
            float4 b = s[part * 8 + k][j];
            a.x += b.x; a.y += b.y; a.z += b.z; a.w += b.w;
        }
        s2[part][j] = a;
    }
    __syncthreads();
    if (threadIdx.x < 8) {
        int j = threadIdx.x;
        float4 a = make_float4(0.f, 0.f, 0.f, 0.f);
#pragma unroll
        for (int k = 0; k < 8; ++k) {
            float4 b = s2[k][j];
            a.x += b.x; a.y += b.y; a.z += b.z; a.w += b.w;
        }
        *(float4*)&partial[(long)blockIdx.x * ZZDIM + j * 4] = a;
    }
}

// sum BPG partials per graph -> pooled -> logits
__global__ void finalize_kernel(const float* __restrict__ partial, const int* __restrict__ lb,
                                const float* __restrict__ bc, const float* __restrict__ Wr,
                                float* __restrict__ out) {
    int g = blockIdx.x;
    int t = threadIdx.x;  // 64 threads
    __shared__ float p[ZZDIM];
    if (t < ZZDIM) {
        float a = 0.f;
#pragma unroll
        for (int q = 0; q < BPG; ++q) a += partial[(long)(g * BPG + q) * ZZDIM + t];
        float c = (float)(lb[g + 1] - lb[g]);
        float v = (c > 0.f) ? (bc[t] + a / c) : 0.f;
        out[g * ZZDIM + t] = v;
        p[t] = v;
    }
    __syncthreads();
    float a = 0.f;
#pragma unroll
    for (int zz = 0; zz < ZZDIM; ++zz) a += p[zz] * Wr[zz * KK + t];
    out[GG * ZZDIM + g * KK + t] = a;
}

// ---------------- launch ----------------

extern "C" void kernel_launch(void* const* d_in, const int* in_sizes, int n_in,
                              void* d_out, int out_size, void* d_ws, size_t ws_size,
                              hipStream_t stream) {
    const int*   x     = (const int*)d_in[0];
    const int*   ei    = (const int*)d_in[1];   // [2,E]: rows then cols
    const float* ew    = (const float*)d_in[2];
    const int*   batch = (const int*)d_in[3];
    const float* emb   = (const float*)d_in[4];
    const float* Wc    = (const float*)d_in[5];
    const float* bc    = (const float*)d_in[6];
    const float* Wr    = (const float*)d_in[7];
    float* out = (float*)d_out;

    const int n = in_sizes[0];
    const int e = in_sizes[2];

    float* ws   = (float*)d_ws;
    __half2* hs16 = (__half2*)ws;            // n*16 half2 = 16n words (16 B aligned)
    float* dinv = ws + 16L * n;              // n
    int*  lb    = (int*)(ws + 17L * n);      // GG+1
    int*  gcur  = lb + GG + 1;               // GG
    long rbase = 17L * n + (2 * GG + 1);
    rbase = (rbase + 63) & ~63L;
    float2* rec = (float2*)(ws + rbase);     // GG*CAP records (8 B each)
    long pbase = rbase + 2L * GG * CAP;
    pbase = (pbase + 63) & ~63L;
    float* partial = ws + pbase;             // SGRID*32 floats

    lb_kernel<<<1, 256, 0, stream>>>(batch, lb, gcur, n);
    bucket_kernel<<<(e + 8191) / 8192, 512, 0, stream>>>(ei, ei + e, ew, batch, lb, gcur, rec, e);
    degB_kernel<<<GG, 256, 0, stream>>>(rec, gcur, lb, dinv);
    hs_kernel<<<(n * 16 + 255) / 256, 256, 0, stream>>>(x, emb, Wc, dinv, hs16, n);
    scatter_kernel<<<SGRID, 512, 0, stream>>>(rec, gcur, lb, dinv, (const uint2*)hs16, partial);
    finalize_kernel<<<GG, KK, 0, stream>>>(partial, lb, bc, Wr, out);
}